// Round 1
// baseline (357.988 us; speedup 1.0000x reference)
//
#include <hip/hip_runtime.h>

// Problem constants (from reference)
constexpr int   NXYZ   = 96;
constexpr int   SY     = 96;            // y stride (elements)
constexpr int   SZ     = 96 * 96;       // z stride
constexpr int   VOL    = 96 * 96 * 96;  // 884736
constexpr int   NT_IN  = 8;             // time steps in input
constexpr int   NT     = 7;             // residual time steps
constexpr int   NB     = 2;
constexpr int   NTOT   = NB * NT * VOL; // 12386304
constexpr float DTI    = 100.0f;        // 1/DT
constexpr float INVH   = 10.0f;         // 1/h
constexpr float INV2H  = 5.0f;          // 1/(2h)
constexpr float INV2H2 = 50.0f;         // 1/(2h^2)
constexpr float INV4H2 = 25.0f;         // 1/(4h^2)
constexpr float D_EFF  = 0.001f;

// jnp.gradient applied twice along one axis (N=96).
// Interior (2..93): (c[i+2] - 2c[i] + c[i-2]) / (4h^2)
// i==0 : (c[2] - 2c[1] + c[0]) / (2h^2)
// i==1 : (c[3] - 3c[1] + 2c[0]) / (4h^2)
// i==94: (2c[95] - 3c[94] + c[92]) / (4h^2)
// i==95: (c[95] - 2c[94] + c[93]) / (2h^2)
__device__ __forceinline__ float lap1d(const float* __restrict__ c, int s, int i, int stride) {
    if (i >= 2 && i <= 93) return (c[s + 2*stride] - 2.0f*c[s] + c[s - 2*stride]) * INV4H2;
    if (i == 0)            return (c[s + 2*stride] - 2.0f*c[s + stride] + c[s]) * INV2H2;
    if (i == 1)            return (c[s + 2*stride] - 3.0f*c[s] + 2.0f*c[s - stride]) * INV4H2;
    if (i == 94)           return (2.0f*c[s + stride] - 3.0f*c[s] + c[s - 2*stride]) * INV4H2;
    /* i == 95 */          return (c[s] - 2.0f*c[s - stride] + c[s - 2*stride]) * INV2H2;
}

// jnp.gradient of (u*c) along one axis (single application).
__device__ __forceinline__ float dflux(const float* __restrict__ c, const float* __restrict__ u,
                                       int s, int i, int stride) {
    if (i == 0)  return (u[s + stride]*c[s + stride] - u[s]*c[s]) * INVH;
    if (i == 95) return (u[s]*c[s] - u[s - stride]*c[s - stride]) * INVH;
    return (u[s + stride]*c[s + stride] - u[s - stride]*c[s - stride]) * INV2H;
}

__global__ __launch_bounds__(256) void resid_kernel(
    const float* __restrict__ c_pred, const float* __restrict__ u_future,
    const float* __restrict__ mask, float* __restrict__ partial) {
    const int tid = threadIdx.x;
    const int gstride = gridDim.x * 256;
    float acc = 0.0f;

    for (int idx = blockIdx.x * 256 + tid; idx < NTOT; idx += gstride) {
        int x = idx % NXYZ;
        int r = idx / NXYZ;
        int y = r % NXYZ; r /= NXYZ;
        int z = r % NXYZ; r /= NXYZ;
        int t = r % NT;
        int b = r / NT;

        const int s = z * SZ + y * SY + x;
        const float* ct   = c_pred + (b * NT_IN + t + 1) * VOL;
        const float* ctm1 = c_pred + (b * NT_IN + t) * VOL;
        const float* ux   = u_future + ((b * NT_IN + t + 1) * 3 + 0) * VOL;
        const float* uy   = ux + VOL;
        const float* uz   = uy + VOL;

        float cc   = ct[s];
        float dcdt = (cc - ctm1[s]) * DTI;

        float div = dflux(ct, ux, s, z, SZ)
                  + dflux(ct, uy, s, y, SY)
                  + dflux(ct, uz, s, x, 1);

        float lap = lap1d(ct, s, z, SZ)
                  + lap1d(ct, s, y, SY)
                  + lap1d(ct, s, x, 1);

        float res = (dcdt + div - D_EFF * lap) * mask[b * VOL + s];
        acc += res * res;
    }

    // wave64 reduce
    #pragma unroll
    for (int off = 32; off > 0; off >>= 1) acc += __shfl_down(acc, off, 64);

    __shared__ float smem[4];
    const int lane = tid & 63, wid = tid >> 6;
    if (lane == 0) smem[wid] = acc;
    __syncthreads();
    if (tid == 0) partial[blockIdx.x] = smem[0] + smem[1] + smem[2] + smem[3];
}

__global__ __launch_bounds__(256) void final_reduce(
    const float* __restrict__ partial, int n, float* __restrict__ out) {
    float s = 0.0f;
    for (int i = threadIdx.x; i < n; i += 256) s += partial[i];
    #pragma unroll
    for (int off = 32; off > 0; off >>= 1) s += __shfl_down(s, off, 64);
    __shared__ float smem[4];
    const int lane = threadIdx.x & 63, wid = threadIdx.x >> 6;
    if (lane == 0) smem[wid] = s;
    __syncthreads();
    if (threadIdx.x == 0) out[0] = (smem[0] + smem[1] + smem[2] + smem[3]) * (1.0f / (float)NTOT);
}

extern "C" void kernel_launch(void* const* d_in, const int* in_sizes, int n_in,
                              void* d_out, int out_size, void* d_ws, size_t ws_size,
                              hipStream_t stream) {
    const float* c_pred   = (const float*)d_in[0];
    const float* u_future = (const float*)d_in[1];
    const float* mask     = (const float*)d_in[2];
    float* out     = (float*)d_out;
    float* partial = (float*)d_ws;

    const int nblocks = 2048;
    resid_kernel<<<nblocks, 256, 0, stream>>>(c_pred, u_future, mask, partial);
    final_reduce<<<1, 256, 0, stream>>>(partial, nblocks, out);
}

// Round 2
// 288.081 us; speedup vs baseline: 1.2427x; 1.2427x over previous
//
#include <hip/hip_runtime.h>

// Geometry
constexpr int   NX    = 96;
constexpr int   SY    = 96;
constexpr int   SZ    = 96 * 96;
constexpr int   VOL   = 96 * 96 * 96;
constexpr int   NT_IN = 8;
constexpr int   NT    = 7;
constexpr int   NB    = 2;
constexpr int   NTOT  = NB * NT * VOL;      // 12386304
constexpr int   YG    = 8;                  // y rows per slab
constexpr int   NYG   = NX / YG;            // 12
constexpr int   NSLAB = NB * NT * NX * NYG; // 16128
constexpr int   TX    = 24;                 // threads along x (4 floats each)
constexpr int   BLK   = TX * YG;            // 192 threads = 3 waves
constexpr int   NBLOCKS = 2048;

constexpr float DTI    = 100.0f;
constexpr float INVH   = 10.0f;
constexpr float INV2H  = 5.0f;
constexpr float INV2H2 = 50.0f;
constexpr float INV4H2 = 25.0f;
constexpr float D_EFF  = 0.001f;

__device__ __forceinline__ void ld4(float* d, const float* __restrict__ p) {
    *(float4*)d = *(const float4*)p;
}

__global__ __launch_bounds__(BLK) void resid_kernel(
    const float* __restrict__ c_pred, const float* __restrict__ u_future,
    const float* __restrict__ mask, float* __restrict__ partial) {
    const int tid = threadIdx.x;
    const int tx  = tid % TX;       // 0..23
    const int ty  = tid / TX;       // 0..7
    float acc = 0.0f;

    for (int slab = blockIdx.x; slab < NSLAB; slab += NBLOCKS) {
        const int yg = slab % NYG;
        int r = slab / NYG;
        const int zz = r % NX; r /= NX;
        const int t  = r % NT;
        const int b  = r / NT;

        const int y  = yg * YG + ty;
        const int xb = tx * 4;
        const int s  = zz * SZ + y * SY + xb;

        const float* ct   = c_pred + (b * NT_IN + t + 1) * VOL;
        const float* ctm1 = ct - VOL;
        const float* ux   = u_future + ((b * NT_IN + t + 1) * 3) * VOL;
        const float* uyp_ = ux + VOL;
        const float* uzp_ = uyp_ + VOL;
        const float* mk   = mask + b * VOL;

        // clamped neighbor offsets (clamped loads are only consumed by
        // boundary formulas that don't reference the clamped slot)
        const int ozm1 = (zz > 0)  ? -SZ     : 0;
        const int ozp1 = (zz < 95) ?  SZ     : 0;
        const int ozm2 = (zz > 1)  ? -2 * SZ : 0;
        const int ozp2 = (zz < 94) ?  2 * SZ : 0;
        const int oym1 = (y > 0)   ? -SY     : 0;
        const int oyp1 = (y < 95)  ?  SY     : 0;
        const int oym2 = (y > 1)   ? -2 * SY : 0;
        const int oyp2 = (y < 94)  ?  2 * SY : 0;
        const int oxl  = (tx > 0)  ? -4      : 0;
        const int oxr  = (tx < TX - 1) ? 4   : 0;

        float cC[4], cL[4], cR[4], cm1[4];
        float czm1[4], czp1[4], czm2[4], czp2[4];
        float cym1[4], cyp1[4], cym2[4], cyp2[4];
        float uxm[4], uxp[4], uym[4], uyp[4];
        float uzL[4], uzC[4], uzR[4], mv[4];

        ld4(cC,   ct + s);
        ld4(cL,   ct + s + oxl);
        ld4(cR,   ct + s + oxr);
        ld4(cm1,  ctm1 + s);
        ld4(czm1, ct + s + ozm1);
        ld4(czp1, ct + s + ozp1);
        ld4(czm2, ct + s + ozm2);
        ld4(czp2, ct + s + ozp2);
        ld4(cym1, ct + s + oym1);
        ld4(cyp1, ct + s + oyp1);
        ld4(cym2, ct + s + oym2);
        ld4(cyp2, ct + s + oyp2);
        ld4(uxm,  ux + s + ozm1);
        ld4(uxp,  ux + s + ozp1);
        ld4(uym,  uyp_ + s + oym1);
        ld4(uyp,  uyp_ + s + oyp1);
        ld4(uzL,  uzp_ + s + oxl);
        ld4(uzC,  uzp_ + s);
        ld4(uzR,  uzp_ + s + oxr);
        ld4(mv,   mk + s);

        // x-direction windows: c and uz at x in [xb-2, xb+5]
        float ax[8], uz8[8];
        ax[0] = cL[2];  ax[1] = cL[3];
        ax[2] = cC[0];  ax[3] = cC[1];  ax[4] = cC[2];  ax[5] = cC[3];
        ax[6] = cR[0];  ax[7] = cR[1];
        uz8[0] = uzL[2]; uz8[1] = uzL[3];
        uz8[2] = uzC[0]; uz8[3] = uzC[1]; uz8[4] = uzC[2]; uz8[5] = uzC[3];
        uz8[6] = uzR[0]; uz8[7] = uzR[1];

        // clamped-load trick: at boundaries the "m1/p1" slots alias center,
        // so flux = f*(u_p1*c_p1 - u_m1*c_m1) with f = 1/h instead of 1/2h.
        const float fz = (zz == 0 || zz == 95) ? INVH : INV2H;
        const float fy = (y  == 0 || y  == 95) ? INVH : INV2H;

        #pragma unroll
        for (int j = 0; j < 4; ++j) {
            const int x  = xb + j;
            const int xi = j + 2;

            float dcdt = (cC[j] - cm1[j]) * DTI;

            float flux = fz * (uxp[j] * czp1[j] - uxm[j] * czm1[j])
                       + fy * (uyp[j] * cyp1[j] - uym[j] * cym1[j]);
            const int xp = (x < 95) ? xi + 1 : xi;
            const int xm = (x > 0)  ? xi - 1 : xi;
            const float fx = (x == 0 || x == 95) ? INVH : INV2H;
            flux += fx * (uz8[xp] * ax[xp] - uz8[xm] * ax[xm]);

            float lap;
            if      (zz == 0)  lap = (czp2[j] - 2.0f * czp1[j] + cC[j])   * INV2H2;
            else if (zz == 1)  lap = (czp2[j] - 3.0f * cC[j] + 2.0f * czm1[j]) * INV4H2;
            else if (zz == 94) lap = (2.0f * czp1[j] - 3.0f * cC[j] + czm2[j]) * INV4H2;
            else if (zz == 95) lap = (cC[j] - 2.0f * czm1[j] + czm2[j]) * INV2H2;
            else               lap = (czp2[j] - 2.0f * cC[j] + czm2[j]) * INV4H2;

            if      (y == 0)   lap += (cyp2[j] - 2.0f * cyp1[j] + cC[j])  * INV2H2;
            else if (y == 1)   lap += (cyp2[j] - 3.0f * cC[j] + 2.0f * cym1[j]) * INV4H2;
            else if (y == 94)  lap += (2.0f * cyp1[j] - 3.0f * cC[j] + cym2[j]) * INV4H2;
            else if (y == 95)  lap += (cC[j] - 2.0f * cym1[j] + cym2[j]) * INV2H2;
            else               lap += (cyp2[j] - 2.0f * cC[j] + cym2[j]) * INV4H2;

            if      (x == 0)   lap += (ax[4] - 2.0f * ax[3] + ax[2]) * INV2H2;
            else if (x == 1)   lap += (ax[5] - 3.0f * ax[3] + 2.0f * ax[2]) * INV4H2;
            else if (x == 94)  lap += (2.0f * ax[5] - 3.0f * ax[4] + ax[2]) * INV4H2;
            else if (x == 95)  lap += (ax[5] - 2.0f * ax[4] + ax[3]) * INV2H2;
            else               lap += (ax[xi + 2] - 2.0f * ax[xi] + ax[xi - 2]) * INV4H2;

            const float res = (dcdt + flux - D_EFF * lap) * mv[j];
            acc += res * res;
        }
    }

    // 3-wave block reduction
    #pragma unroll
    for (int off = 32; off > 0; off >>= 1) acc += __shfl_down(acc, off, 64);
    __shared__ float smem[3];
    const int lane = tid & 63, wid = tid >> 6;
    if (lane == 0) smem[wid] = acc;
    __syncthreads();
    if (tid == 0) partial[blockIdx.x] = smem[0] + smem[1] + smem[2];
}

__global__ __launch_bounds__(256) void final_reduce(
    const float* __restrict__ partial, int n, float* __restrict__ out) {
    float s = 0.0f;
    for (int i = threadIdx.x; i < n; i += 256) s += partial[i];
    #pragma unroll
    for (int off = 32; off > 0; off >>= 1) s += __shfl_down(s, off, 64);
    __shared__ float smem[4];
    const int lane = threadIdx.x & 63, wid = threadIdx.x >> 6;
    if (lane == 0) smem[wid] = s;
    __syncthreads();
    if (threadIdx.x == 0)
        out[0] = (smem[0] + smem[1] + smem[2] + smem[3]) * (1.0f / (float)NTOT);
}

extern "C" void kernel_launch(void* const* d_in, const int* in_sizes, int n_in,
                              void* d_out, int out_size, void* d_ws, size_t ws_size,
                              hipStream_t stream) {
    const float* c_pred   = (const float*)d_in[0];
    const float* u_future = (const float*)d_in[1];
    const float* mask     = (const float*)d_in[2];
    float* out     = (float*)d_out;
    float* partial = (float*)d_ws;

    resid_kernel<<<NBLOCKS, BLK, 0, stream>>>(c_pred, u_future, mask, partial);
    final_reduce<<<1, 256, 0, stream>>>(partial, NBLOCKS, out);
}

// Round 3
// 279.193 us; speedup vs baseline: 1.2822x; 1.0318x over previous
//
#include <hip/hip_runtime.h>

// Geometry
constexpr int   NX    = 96;
constexpr int   SY    = 96;
constexpr int   SZ    = 96 * 96;
constexpr int   VOL   = 96 * 96 * 96;
constexpr int   NT_IN = 8;
constexpr int   NT    = 7;
constexpr int   NB    = 2;
constexpr int   NTOT  = NB * NT * VOL;   // 12386304
constexpr int   TX    = 24;              // threads along x, 4 floats each
constexpr int   YG    = 8;               // y rows per block
constexpr int   BLK   = TX * YG;         // 192 threads
constexpr int   ZC    = 8;               // z planes marched per block
constexpr int   NZC   = NX / ZC;         // 12
constexpr int   NYG   = NX / YG;         // 12
constexpr int   NBLK  = NB * NT * NYG * NZC; // 2016

constexpr float DTI    = 100.0f;
constexpr float INVH   = 10.0f;
constexpr float INV2H  = 5.0f;
constexpr float INV2H2 = 50.0f;
constexpr float INV4H2 = 25.0f;
constexpr float D_EFF  = 0.001f;

__device__ __forceinline__ void ld4(float* d, const float* __restrict__ p) {
    *(float4*)d = *(const float4*)p;
}

// 5-tap weights for gradient(gradient(.)) over taps (m2,m1,c,p1,p2), axis size 96.
__device__ __forceinline__ void wts5(int i, float* w) {
    if (i == 0)       { w[0]=0.f;     w[1]=0.f;          w[2]=INV2H2;       w[3]=-2.f*INV2H2; w[4]=INV2H2; }
    else if (i == 1)  { w[0]=0.f;     w[1]=2.f*INV4H2;   w[2]=-3.f*INV4H2;  w[3]=0.f;         w[4]=INV4H2; }
    else if (i == 94) { w[0]=INV4H2;  w[1]=0.f;          w[2]=-3.f*INV4H2;  w[3]=2.f*INV4H2;  w[4]=0.f;    }
    else if (i == 95) { w[0]=INV2H2;  w[1]=-2.f*INV2H2;  w[2]=INV2H2;       w[3]=0.f;         w[4]=0.f;    }
    else              { w[0]=INV4H2;  w[1]=0.f;          w[2]=-2.f*INV4H2;  w[3]=0.f;         w[4]=INV4H2; }
}

__global__ __launch_bounds__(BLK) void resid_kernel(
    const float* __restrict__ c_pred, const float* __restrict__ u_future,
    const float* __restrict__ mask, float* __restrict__ partial) {
    const int tid = threadIdx.x;
    const int tx  = tid % TX;        // 0..23
    const int ty  = tid / TX;        // 0..7

    // Block decode (once, all compile-time divisors)
    int bid = blockIdx.x;
    const int yg = bid % NYG;  bid /= NYG;
    const int zc = bid % NZC;  bid /= NZC;
    const int t  = bid % NT;
    const int b  = bid / NT;
    const int z0 = zc * ZC;
    const int y  = yg * YG + ty;
    const int xb = tx * 4;

    // Region bases (uniform)
    const float* ct   = c_pred + (size_t)(b * NT_IN + t + 1) * VOL;
    const float* ctm1 = ct - VOL;
    const float* ux   = u_future + (size_t)((b * NT_IN + t + 1) * 3) * VOL;
    const float* uyb  = ux + VOL;
    const float* uzb  = uyb + VOL;
    const float* mkb  = mask + (size_t)b * VOL;

    // Per-thread voffsets (loop-invariant, elements)
    const int vc   = y * SY + xb;
    const int vxl  = vc + ((tx > 0)      ? -4 : 0);
    const int vxr  = vc + ((tx < TX - 1) ?  4 : 0);
    const int vym1 = ((y > 0)  ? y - 1 : 0) * SY + xb;
    const int vyp1 = ((y < 95) ? y + 1 : 95) * SY + xb;
    const int vym2 = ((y > 1)  ? y - 2 : 0) * SY + xb;
    const int vyp2 = ((y < 94) ? y + 2 : 95) * SY + xb;

    // Hoisted per-thread weights
    float wy[5];
    wts5(y, wy);
    const float fy = (y == 0 || y == 95) ? INVH : INV2H;
    float wx[4][5];
    #pragma unroll
    for (int j = 0; j < 4; ++j) wts5(xb + j, wx[j]);

    // Prime rotating plane state (clamped at the low end)
    const int zm2 = (z0 >= 2) ? z0 - 2 : 0;
    const int zm1 = (z0 >= 1) ? z0 - 1 : 0;
    float czm2[4], czm1[4], cc[4], czp1[4], czp2[4];
    float uxm[4], uxc[4], uxp[4];
    ld4(czm2, ct + zm2 * SZ + vc);
    ld4(czm1, ct + zm1 * SZ + vc);
    ld4(cc,   ct + z0 * SZ + vc);
    ld4(czp1, ct + (z0 + 1) * SZ + vc);
    ld4(uxm,  ux + zm1 * SZ + vc);
    ld4(uxc,  ux + z0 * SZ + vc);

    float acc = 0.0f;

    #pragma unroll 2
    for (int iz = 0; iz < ZC; ++iz) {
        const int z    = z0 + iz;          // uniform
        const int zoff = z * SZ;
        const int zp2  = (z < 94) ? z + 2 : 95;
        const int zp1  = (z < 95) ? z + 1 : 95;

        // 15 independent ld4 (addresses = SGPR base/plane + invariant voffset)
        float cL[4], cR[4], cym1[4], cyp1[4], cym2[4], cyp2[4];
        float uym[4], uyp[4], uzL[4], uzC[4], uzR[4], cm1[4], mv[4];
        ld4(czp2, ct + zp2 * SZ + vc);
        ld4(uxp,  ux + zp1 * SZ + vc);
        ld4(cL,   ct + zoff + vxl);
        ld4(cR,   ct + zoff + vxr);
        ld4(cym1, ct + zoff + vym1);
        ld4(cyp1, ct + zoff + vyp1);
        ld4(cym2, ct + zoff + vym2);
        ld4(cyp2, ct + zoff + vyp2);
        ld4(uym,  uyb + zoff + vym1);
        ld4(uyp,  uyb + zoff + vyp1);
        ld4(uzL,  uzb + zoff + vxl);
        ld4(uzC,  uzb + zoff + vc);
        ld4(uzR,  uzb + zoff + vxr);
        ld4(cm1,  ctm1 + zoff + vc);
        ld4(mv,   mkb + zoff + vc);

        // Per-step uniform z weights / factor
        float wz[5];
        wts5(z, wz);
        const float fz = (z == 0 || z == 95) ? INVH : INV2H;

        // x windows (static indexing only): ax[k] = c at x = xb-2+k
        float ax[8], uzw[8];
        ax[0] = cL[2];  ax[1] = cL[3];
        ax[2] = cc[0];  ax[3] = cc[1];  ax[4] = cc[2];  ax[5] = cc[3];
        ax[6] = cR[0];  ax[7] = cR[1];
        uzw[0] = uzL[2]; uzw[1] = uzL[3];
        uzw[2] = uzC[0]; uzw[3] = uzC[1]; uzw[4] = uzC[2]; uzw[5] = uzC[3];
        uzw[6] = uzR[0]; uzw[7] = uzR[1];
        float P[7];
        #pragma unroll
        for (int k = 1; k <= 6; ++k) P[k] = uzw[k] * ax[k];

        #pragma unroll
        for (int j = 0; j < 4; ++j) {
            const float dc  = (cc[j] - cm1[j]) * DTI;
            const float fzv = (uxp[j] * czp1[j] - uxm[j] * czm1[j]) * fz;
            const float fyv = (uyp[j] * cyp1[j] - uym[j] * cym1[j]) * fy;
            float fxv = (P[j + 3] - P[j + 1]) * INV2H;
            if (j == 0) fxv = (xb == 0)  ? (P[3] - P[2]) * INVH : fxv;
            if (j == 3) fxv = (xb == 92) ? (P[5] - P[4]) * INVH : fxv;

            float lap = wz[0]*czm2[j] + wz[1]*czm1[j] + wz[2]*cc[j] + wz[3]*czp1[j] + wz[4]*czp2[j];
            lap += wy[0]*cym2[j] + wy[1]*cym1[j] + wy[2]*cc[j] + wy[3]*cyp1[j] + wy[4]*cyp2[j];
            lap += wx[j][0]*ax[j] + wx[j][1]*ax[j+1] + wx[j][2]*ax[j+2]
                 + wx[j][3]*ax[j+3] + wx[j][4]*ax[j+4];

            const float r = (dc + fzv + fyv + fxv - D_EFF * lap) * mv[j];
            acc += r * r;
        }

        // Rotate plane state
        #pragma unroll
        for (int q = 0; q < 4; ++q) {
            czm2[q] = czm1[q]; czm1[q] = cc[q]; cc[q] = czp1[q]; czp1[q] = czp2[q];
            uxm[q] = uxc[q];   uxc[q] = uxp[q];
        }
    }

    // 3-wave block reduction
    #pragma unroll
    for (int off = 32; off > 0; off >>= 1) acc += __shfl_down(acc, off, 64);
    __shared__ float smem[3];
    const int lane = tid & 63, wid = tid >> 6;
    if (lane == 0) smem[wid] = acc;
    __syncthreads();
    if (tid == 0) partial[blockIdx.x] = smem[0] + smem[1] + smem[2];
}

__global__ __launch_bounds__(256) void final_reduce(
    const float* __restrict__ partial, int n, float* __restrict__ out) {
    float s = 0.0f;
    for (int i = threadIdx.x; i < n; i += 256) s += partial[i];
    #pragma unroll
    for (int off = 32; off > 0; off >>= 1) s += __shfl_down(s, off, 64);
    __shared__ float smem[4];
    const int lane = threadIdx.x & 63, wid = threadIdx.x >> 6;
    if (lane == 0) smem[wid] = s;
    __syncthreads();
    if (threadIdx.x == 0)
        out[0] = (smem[0] + smem[1] + smem[2] + smem[3]) * (1.0f / (float)NTOT);
}

extern "C" void kernel_launch(void* const* d_in, const int* in_sizes, int n_in,
                              void* d_out, int out_size, void* d_ws, size_t ws_size,
                              hipStream_t stream) {
    const float* c_pred   = (const float*)d_in[0];
    const float* u_future = (const float*)d_in[1];
    const float* mask     = (const float*)d_in[2];
    float* out     = (float*)d_out;
    float* partial = (float*)d_ws;

    resid_kernel<<<NBLK, BLK, 0, stream>>>(c_pred, u_future, mask, partial);
    final_reduce<<<1, 256, 0, stream>>>(partial, NBLK, out);
}